// Round 6
// baseline (256.720 us; speedup 1.0000x reference)
//
#include <hip/hip_runtime.h>
#include <math.h>

#define B_ 32
#define L_ 2048
#define D_ 512
#define K_ 512
#define CONC_ 100.0f
#define EPS_ 1e-12f
#define LSPLIT 16   // 16 chunks of 128 l's (= GEMM l-tile)

typedef __attribute__((ext_vector_type(8))) _Float16 f16x8;
typedef __attribute__((ext_vector_type(4))) _Float16 f16x4;
typedef __attribute__((ext_vector_type(4))) float f32x4;

// ---- workspace layout (float offsets) ----
enum : size_t {
  O_SCALE = 0,                          // B*D  (raw sum_l x^2, accumulated)
  O_MEANC = O_SCALE + B_*D_,            // D
  O_PM    = O_MEANC + D_,               // B*LSPLIT*K  (chunk max)
  O_PS    = O_PM + (size_t)B_*LSPLIT*K_,// B*LSPLIT*K  (chunk sum)
  O_WX    = O_PS + (size_t)B_*LSPLIT*K_,// B*D
  O_CF16  = O_WX + B_*D_,               // K*D halfs   = 131072 floats
  O_DIR   = O_CF16 + (size_t)K_*D_/2,   // B*L*D halfs
  O_L16   = O_DIR + (size_t)B_*L_*D_/2, // B*L*K halfs (shifted logits)
  WS_FLOATS = O_L16 + (size_t)B_*L_*K_/2
};

// merged prep: centhalf (blocks 0..255), meanc (256..257),
// zero scale (258..321), zero wx (322..385)
__global__ void k_prep(const float* __restrict__ cent, float* ws) {
  int blk = blockIdx.x, tid = threadIdx.x;
  if (blk < 256) {
    int i = (blk * 256 + tid) * 4;
    float4 v = *reinterpret_cast<const float4*>(cent + i);
    f16x4 h;
    h[0] = (_Float16)(v.x * (2.f * CONC_));
    h[1] = (_Float16)(v.y * (2.f * CONC_));
    h[2] = (_Float16)(v.z * (2.f * CONC_));
    h[3] = (_Float16)(v.w * (2.f * CONC_));
    *reinterpret_cast<f16x4*>(reinterpret_cast<_Float16*>(ws + O_CF16) + i) = h;
  } else if (blk < 258) {
    int d = (blk - 256) * 256 + tid;
    float s = 0.f;
    for (int k = 0; k < K_; ++k) s += cent[(size_t)k * D_ + d];
    ws[O_MEANC + d] = s * (1.f / K_);
  } else if (blk < 322) {
    ws[O_SCALE + (blk - 258) * 256 + tid] = 0.f;
  } else {
    ws[O_WX + (blk - 322) * 256 + tid] = 0.f;
  }
}

// accumulate sum_l x^2 into scale (raw, not divided)
__global__ void k_sqacc(const float* __restrict__ x, float* ws) {
  int b = blockIdx.x, dc = blockIdx.y, lc = blockIdx.z;
  int d = dc * 256 + threadIdx.x;
  const float* xb = x + ((size_t)b * L_ + lc * 256) * D_ + d;
  float acc = 0.f;
  for (int l = 0; l < 256; ++l) {
    float v = xb[(size_t)l * D_];
    acc += v * v;
  }
  atomicAdd(&ws[O_SCALE + b * D_ + d], acc);
}

// dir16[b,l,d] = fp16(x / max(scale,eps)), inv computed on the fly
__global__ void k_dir16(const float* __restrict__ x, float* ws) {
  size_t i = ((size_t)blockIdx.x * 256 + threadIdx.x) * 8;
  int d8 = (int)(i & (D_ - 1));
  int b = (int)(i >> 20);                 // L_*D_ = 2^20
  float4 x0 = *reinterpret_cast<const float4*>(x + i);
  float4 x1 = *reinterpret_cast<const float4*>(x + i + 4);
  const float* sb = ws + O_SCALE + (size_t)b * D_ + d8;
  float4 s0 = *reinterpret_cast<const float4*>(sb);
  float4 s1 = *reinterpret_cast<const float4*>(sb + 4);
  f16x8 h;
  h[0] = (_Float16)(x0.x / fmaxf(s0.x * (1.f / L_), EPS_));
  h[1] = (_Float16)(x0.y / fmaxf(s0.y * (1.f / L_), EPS_));
  h[2] = (_Float16)(x0.z / fmaxf(s0.z * (1.f / L_), EPS_));
  h[3] = (_Float16)(x0.w / fmaxf(s0.w * (1.f / L_), EPS_));
  h[4] = (_Float16)(x1.x / fmaxf(s1.x * (1.f / L_), EPS_));
  h[5] = (_Float16)(x1.y / fmaxf(s1.y * (1.f / L_), EPS_));
  h[6] = (_Float16)(x1.z / fmaxf(s1.z * (1.f / L_), EPS_));
  h[7] = (_Float16)(x1.w / fmaxf(s1.w * (1.f / L_), EPS_));
  *reinterpret_cast<f16x8*>(reinterpret_cast<_Float16*>(ws + O_DIR) + i) = h;
}

// MFMA GEMM, fragments loaded DIRECTLY from global (no LDS, no K-loop
// barriers). Both operands are [row][d] with d contiguous; the 16x16x32
// fragment = 16B/lane at row (lane&15), k-slot (lane>>4) — a natural
// global_load_dwordx4 pattern. 128x128 tile, 4 waves, wave = 64x64.
// Fused per-chunk softmax partials + fp16 shifted-logit store.
__global__ __launch_bounds__(256) void k_gemm16(float* ws) {
  const int b = blockIdx.z;
  const int l0 = blockIdx.x * 128;
  const int k0 = blockIdx.y * 128;
  const int tid = threadIdx.x;
  const int lane = tid & 63;
  const int w = tid >> 6;
  const int wm = w >> 1, wn = w & 1;

  const _Float16* cf = reinterpret_cast<const _Float16*>(ws + O_CF16);
  const _Float16* db = reinterpret_cast<const _Float16*>(ws + O_DIR) +
                       (size_t)b * L_ * D_;

  const int r = lane & 15;            // row within fragment
  const int ks = (lane >> 4) * 8;     // k-slot offset (halfs)
  const _Float16* aptr = db + (size_t)(l0 + wm * 64 + r) * D_ + ks;
  const _Float16* bptr = cf + (size_t)(k0 + wn * 64 + r) * D_ + ks;

  f32x4 acc[4][4] = {};

#pragma unroll 4
  for (int d0 = 0; d0 < D_; d0 += 32) {
    f16x8 af[4], bfr[4];
#pragma unroll
    for (int mi = 0; mi < 4; ++mi)
      af[mi] = *reinterpret_cast<const f16x8*>(aptr + (size_t)mi * 16 * D_ + d0);
#pragma unroll
    for (int ni = 0; ni < 4; ++ni)
      bfr[ni] = *reinterpret_cast<const f16x8*>(bptr + (size_t)ni * 16 * D_ + d0);
#pragma unroll
    for (int mi = 0; mi < 4; ++mi)
#pragma unroll
      for (int ni = 0; ni < 4; ++ni)
        acc[mi][ni] = __builtin_amdgcn_mfma_f32_16x16x32_f16(
            af[mi], bfr[ni], acc[mi][ni], 0, 0, 0);
  }

  // ---- fused softmax partials over this block's 128 l's ----
  // (bias[k] omitted: constant over l, cancels in softmax over l)
  __shared__ float red[256];    // [2 wm][128 k] wave maxes
  __shared__ float red2[256];   // [2 wm][128 k] wave sums
  float pm[4], ps[4];
#pragma unroll
  for (int ni = 0; ni < 4; ++ni) {
    float m = -INFINITY;
#pragma unroll
    for (int mi = 0; mi < 4; ++mi)
#pragma unroll
      for (int j = 0; j < 4; ++j) m = fmaxf(m, acc[mi][ni][j]);
    m = fmaxf(m, __shfl_xor(m, 16));
    m = fmaxf(m, __shfl_xor(m, 32));
    pm[ni] = m;
  }
  if (lane < 16) {
#pragma unroll
    for (int ni = 0; ni < 4; ++ni)
      red[wm * 128 + wn * 64 + ni * 16 + lane] = pm[ni];
  }
  __syncthreads();
#pragma unroll
  for (int ni = 0; ni < 4; ++ni) {
    int idx = wn * 64 + ni * 16 + (lane & 15);
    pm[ni] = fmaxf(red[idx], red[128 + idx]);   // combined chunk max
  }
#pragma unroll
  for (int ni = 0; ni < 4; ++ni) {
    float s = 0.f;
#pragma unroll
    for (int mi = 0; mi < 4; ++mi)
#pragma unroll
      for (int j = 0; j < 4; ++j) s += expf(acc[mi][ni][j] - pm[ni]);
    s += __shfl_xor(s, 16);
    s += __shfl_xor(s, 32);
    ps[ni] = s;
  }
  if (lane < 16) {
#pragma unroll
    for (int ni = 0; ni < 4; ++ni)
      red2[wm * 128 + wn * 64 + ni * 16 + lane] = ps[ni];
  }
  __syncthreads();
  if (w < 2 && lane < 16) {
#pragma unroll
    for (int ni = 0; ni < 4; ++ni) {
      int idx = wn * 64 + ni * 16 + lane;
      float mg = fmaxf(red[idx], red[128 + idx]);
      float sg = red2[idx] + red2[128 + idx];
      size_t o = ((size_t)b * LSPLIT + blockIdx.x) * K_ + k0 + idx;
      ws[O_PM + o] = mg;
      ws[O_PS + o] = sg;
    }
  }
  // store fp16 shifted logits (v - chunk_max), linear [b][l][k]
  _Float16* lg = reinterpret_cast<_Float16*>(ws + O_L16) + (size_t)b * L_ * K_;
#pragma unroll
  for (int ni = 0; ni < 4; ++ni) {
    int kc = k0 + wn * 64 + ni * 16 + (lane & 15);
#pragma unroll
    for (int mi = 0; mi < 4; ++mi) {
      int lr = l0 + wm * 64 + mi * 16 + (lane >> 4) * 4;
#pragma unroll
      for (int j = 0; j < 4; ++j)
        lg[(size_t)(lr + j) * K_ + kc] = (_Float16)(acc[mi][ni][j] - pm[ni]);
    }
  }
}

// fused: recompute chunk->global combine (read-only PM/PS), then
// w[l] = sum_k exp(vshift[l,k])*A[k]; then wx[b,d] += sum_l w[l]*dir[l,d]
__global__ __launch_bounds__(256) void k_wsumwx(float* ws) {
  int b = blockIdx.x, ch = blockIdx.y;
  int l0 = ch * 128;
  __shared__ float wl[128];
  __shared__ float Al[512];
  int tid = threadIdx.x, lane = tid & 63, wv = tid >> 6;

  // combine: A[k] = exp(pm[ch,k] - M[k]) / S[k]
  for (int kk = tid; kk < K_; kk += 256) {
    float pmv[LSPLIT], psv[LSPLIT];
    float M = -INFINITY;
#pragma unroll
    for (int c = 0; c < LSPLIT; ++c) {
      pmv[c] = ws[O_PM + ((size_t)b * LSPLIT + c) * K_ + kk];
      psv[c] = ws[O_PS + ((size_t)b * LSPLIT + c) * K_ + kk];
      M = fmaxf(M, pmv[c]);
    }
    float S = 0.f;
#pragma unroll
    for (int c = 0; c < LSPLIT; ++c) S += psv[c] * expf(pmv[c] - M);
    Al[kk] = expf(pmv[ch] - M) / S;
  }
  __syncthreads();

  const _Float16* lg = reinterpret_cast<const _Float16*>(ws + O_L16) +
                       (size_t)(b * L_ + l0) * K_;
  float a8[8];
#pragma unroll
  for (int i = 0; i < 8; ++i) a8[i] = Al[lane * 8 + i];

  for (int il = 0; il < 32; ++il) {
    int ll = wv * 32 + il;
    f16x8 v = *reinterpret_cast<const f16x8*>(lg + (size_t)ll * K_ + lane * 8);
    float s = 0.f;
#pragma unroll
    for (int i = 0; i < 8; ++i) s += expf((float)v[i]) * a8[i];
#pragma unroll
    for (int off = 32; off > 0; off >>= 1) s += __shfl_xor(s, off);
    if (lane == 0) wl[ll] = s;
  }
  __syncthreads();

  const _Float16* db = reinterpret_cast<const _Float16*>(ws + O_DIR) +
                       (size_t)(b * L_ + l0) * D_;
  int half = tid >> 7;            // 0/1 -> l 0..63 / 64..127
  int dd = (tid & 127) * 4;
  float4 a4 = {0.f, 0.f, 0.f, 0.f};
  for (int l = half * 64; l < half * 64 + 64; ++l) {
    float wgt = wl[l];
    f16x4 dv = *reinterpret_cast<const f16x4*>(db + (size_t)l * D_ + dd);
    a4.x += wgt * (float)dv[0];
    a4.y += wgt * (float)dv[1];
    a4.z += wgt * (float)dv[2];
    a4.w += wgt * (float)dv[3];
  }
  atomicAdd(&ws[O_WX + b * D_ + dd + 0], a4.x);
  atomicAdd(&ws[O_WX + b * D_ + dd + 1], a4.y);
  atomicAdd(&ws[O_WX + b * D_ + dd + 2], a4.z);
  atomicAdd(&ws[O_WX + b * D_ + dd + 3], a4.w);
}

// out[b,d] = (rawscale/L) * (wx/K - meanC[d])
__global__ void k_final(const float* ws, float* out) {
  int i = blockIdx.x * 256 + threadIdx.x;
  int d = i & (D_ - 1);
  out[i] = (ws[O_SCALE + i] * (1.f / L_)) *
           (ws[O_WX + i] * (1.f / K_) - ws[O_MEANC + d]);
}

extern "C" void kernel_launch(void* const* d_in, const int* in_sizes, int n_in,
                              void* d_out, int out_size, void* d_ws, size_t ws_size,
                              hipStream_t stream) {
  const float* x = (const float*)d_in[0];
  const float* cent = (const float*)d_in[1];
  float* out = (float*)d_out;
  float* ws = (float*)d_ws;

  k_prep<<<386, 256, 0, stream>>>(cent, ws);
  k_sqacc<<<dim3(B_, D_ / 256, 8), 256, 0, stream>>>(x, ws);
  k_dir16<<<16384, 256, 0, stream>>>(x, ws);
  k_gemm16<<<dim3(L_ / 128, K_ / 128, B_), 256, 0, stream>>>(ws);
  k_wsumwx<<<dim3(B_, LSPLIT), 256, 0, stream>>>(ws);
  k_final<<<B_ * D_ / 256, 256, 0, stream>>>(ws, out);
}

// Round 7
// 162.794 us; speedup vs baseline: 1.5770x; 1.5770x over previous
//
#include <hip/hip_runtime.h>
#include <math.h>

#define B_ 32
#define L_ 2048
#define D_ 512
#define K_ 512
#define CONC_ 100.0f
#define EPS_ 1e-12f
#define LSPLIT 16   // 16 chunks of 128 l's (= GEMM l-tile)

typedef __attribute__((ext_vector_type(8))) _Float16 f16x8;
typedef __attribute__((ext_vector_type(4))) _Float16 f16x4;
typedef __attribute__((ext_vector_type(4))) float f32x4;

// ---- workspace layout (float offsets) ----
enum : size_t {
  O_SCALE = 0,                          // B*D  (raw sum_l x^2, accumulated)
  O_INV   = O_SCALE + B_*D_,            // B*D  (1/max(scale,eps))
  O_MEANC = O_INV + B_*D_,              // D
  O_PM    = O_MEANC + D_,               // B*LSPLIT*K  (chunk max)
  O_PS    = O_PM + (size_t)B_*LSPLIT*K_,// B*LSPLIT*K  (chunk sum)
  O_WX    = O_PS + (size_t)B_*LSPLIT*K_,// B*D  (raw weighted-x accum)
  O_CF16  = O_WX + B_*D_,               // K*D halfs = 131072 floats
  O_L16   = O_CF16 + (size_t)K_*D_/2,   // B*L*K halfs (shifted logits)
  WS_FLOATS = O_L16 + (size_t)B_*L_*K_/2
};

__device__ __forceinline__ void gl2lds16(const void* gsrc, void* lds) {
  __builtin_amdgcn_global_load_lds(
      (const __attribute__((address_space(1))) void*)gsrc,
      (__attribute__((address_space(3))) void*)lds, 16, 0, 0);
}

// merged prep: centhalf (blocks 0..255), meanc (256..257),
// zero scale (258..321), zero wx (322..385)
__global__ void k_prep(const float* __restrict__ cent, float* ws) {
  int blk = blockIdx.x, tid = threadIdx.x;
  if (blk < 256) {
    int i = (blk * 256 + tid) * 4;
    float4 v = *reinterpret_cast<const float4*>(cent + i);
    f16x4 h;
    h[0] = (_Float16)(v.x * (2.f * CONC_));
    h[1] = (_Float16)(v.y * (2.f * CONC_));
    h[2] = (_Float16)(v.z * (2.f * CONC_));
    h[3] = (_Float16)(v.w * (2.f * CONC_));
    *reinterpret_cast<f16x4*>(reinterpret_cast<_Float16*>(ws + O_CF16) + i) = h;
  } else if (blk < 258) {
    int d = (blk - 256) * 256 + tid;
    float s = 0.f;
    for (int k = 0; k < K_; ++k) s += cent[(size_t)k * D_ + d];
    ws[O_MEANC + d] = s * (1.f / K_);
  } else if (blk < 322) {
    ws[O_SCALE + (blk - 258) * 256 + tid] = 0.f;
  } else {
    ws[O_WX + (blk - 322) * 256 + tid] = 0.f;
  }
}

// accumulate sum_l x^2 into scale (raw, not divided)
__global__ void k_sqacc(const float* __restrict__ x, float* ws) {
  int b = blockIdx.x, dc = blockIdx.y, lc = blockIdx.z;
  int d = dc * 256 + threadIdx.x;
  const float* xb = x + ((size_t)b * L_ + lc * 256) * D_ + d;
  float acc = 0.f;
  for (int l = 0; l < 256; ++l) {
    float v = xb[(size_t)l * D_];
    acc += v * v;
  }
  atomicAdd(&ws[O_SCALE + b * D_ + d], acc);
}

// inv = 1/max(scale/L, eps)
__global__ void k_finscale(float* ws) {
  int i = blockIdx.x * 256 + threadIdx.x;   // B*D = 16384
  ws[O_INV + i] = 1.f / fmaxf(ws[O_SCALE + i] * (1.f / L_), EPS_);
}

// MFMA GEMM + fused per-chunk softmax partials + fp16 shifted-logit store.
// Block = 128 l x 256 k, 4 waves as 1M x 4N: wave = 128 l x 64 k, acc[8][4].
// Each wave owns the FULL l-chunk for its k's -> softmax partials reduce
// in-wave (no LDS, no extra barriers). A staged from x fp32 (*inv, cvt f16).
__global__ __launch_bounds__(256, 2) void k_gemm16(const float* __restrict__ x,
                                                   float* ws) {
  const int b = blockIdx.z;
  const int l0 = blockIdx.x * 128;
  const int k0 = blockIdx.y * 256;
  __shared__ _Float16 As[128 * 32];   // 8 KB, slot-swizzled
  __shared__ _Float16 Bs[256 * 32];   // 16 KB, slot-swizzled
  const int tid = threadIdx.x;
  const int lane = tid & 63;
  const int w = tid >> 6;             // wave = k-quadrant 0..3

  const _Float16* cf = reinterpret_cast<const _Float16*>(ws + O_CF16);
  const float* xb = x + (size_t)b * L_ * D_;
  const float* invb = ws + O_INV + b * D_;

  f32x4 acc[8][4] = {};

  for (int d0 = 0; d0 < D_; d0 += 32) {
    // stage B (cent16): 1024 x 16B units via global_load_lds, pre-swizzled src
#pragma unroll
    for (int r = 0; r < 4; ++r) {
      int u = r * 256 + tid;
      int row = u >> 2, slot = u & 3;
      int sc = (slot ^ ((row >> 1) & 3)) * 8;
      gl2lds16(cf + (size_t)(k0 + row) * D_ + d0 + sc, Bs + (size_t)u * 8);
    }
    // stage A: x fp32 -> *inv -> f16, swizzled ds_write (1024 x 8B units)
#pragma unroll
    for (int r = 0; r < 4; ++r) {
      int f = r * 256 + tid;
      int row = f >> 3;                 // l row 0..127
      int col4 = (f & 7) << 2;          // 0,4,..,28
      float4 xv = *reinterpret_cast<const float4*>(
          xb + (size_t)(l0 + row) * D_ + d0 + col4);
      float4 iv = *reinterpret_cast<const float4*>(invb + d0 + col4);
      f16x4 hv;
      hv[0] = (_Float16)(xv.x * iv.x);
      hv[1] = (_Float16)(xv.y * iv.y);
      hv[2] = (_Float16)(xv.z * iv.z);
      hv[3] = (_Float16)(xv.w * iv.w);
      int slot = col4 >> 3;
      int half = (col4 >> 2) & 1;
      int sw = slot ^ ((row >> 1) & 3);
      *reinterpret_cast<f16x4*>(
          reinterpret_cast<char*>(As) + row * 64 + sw * 16 + half * 8) = hv;
    }
    __syncthreads();

    f16x8 af[8];
#pragma unroll
    for (int mi = 0; mi < 8; ++mi) {
      int row = mi * 16 + (lane & 15);
      int sw = (lane >> 4) ^ ((row >> 1) & 3);
      af[mi] = *reinterpret_cast<const f16x8*>(
          reinterpret_cast<const char*>(As) + row * 64 + sw * 16);
    }
#pragma unroll
    for (int ni = 0; ni < 4; ++ni) {
      int row = w * 64 + ni * 16 + (lane & 15);
      int sw = (lane >> 4) ^ ((row >> 1) & 3);
      f16x8 bf = *reinterpret_cast<const f16x8*>(
          reinterpret_cast<const char*>(Bs) + row * 64 + sw * 16);
#pragma unroll
      for (int mi = 0; mi < 8; ++mi)
        acc[mi][ni] = __builtin_amdgcn_mfma_f32_16x16x32_f16(
            af[mi], bf, acc[mi][ni], 0, 0, 0);
    }
    __syncthreads();
  }

  // ---- fused per-chunk softmax partials, fully in-wave ----
  // (bias[k] omitted: constant over l, cancels in softmax over l)
  _Float16* lg = reinterpret_cast<_Float16*>(ws + O_L16) + (size_t)b * L_ * K_;
#pragma unroll
  for (int ni = 0; ni < 4; ++ni) {
    float m = -INFINITY;
#pragma unroll
    for (int mi = 0; mi < 8; ++mi)
#pragma unroll
      for (int j = 0; j < 4; ++j) m = fmaxf(m, acc[mi][ni][j]);
    m = fmaxf(m, __shfl_xor(m, 16));
    m = fmaxf(m, __shfl_xor(m, 32));      // chunk max over all 128 l's
    float s = 0.f;
#pragma unroll
    for (int mi = 0; mi < 8; ++mi)
#pragma unroll
      for (int j = 0; j < 4; ++j) s += expf(acc[mi][ni][j] - m);
    s += __shfl_xor(s, 16);
    s += __shfl_xor(s, 32);
    int kc = k0 + w * 64 + ni * 16 + (lane & 15);
    if (lane < 16) {
      size_t o = ((size_t)b * LSPLIT + blockIdx.x) * K_ + kc;
      ws[O_PM + o] = m;
      ws[O_PS + o] = s;
    }
    // store fp16 shifted logits (v - chunk_max), linear [b][l][k]
#pragma unroll
    for (int mi = 0; mi < 8; ++mi) {
      int lr = l0 + mi * 16 + (lane >> 4) * 4;
#pragma unroll
      for (int j = 0; j < 4; ++j)
        lg[(size_t)(lr + j) * K_ + kc] = (_Float16)(acc[mi][ni][j] - m);
    }
  }
}

// fused: recompute chunk->global combine (read-only PM/PS), then
// w[l] = sum_k exp(vshift[l,k])*A[k]; then wx[b,d] += sum_l w[l]*x[b,l,d]
// (inv factors out of the weighted sum; applied in k_final)
__global__ __launch_bounds__(256) void k_wsumwx(const float* __restrict__ x,
                                                float* ws) {
  int b = blockIdx.x, ch = blockIdx.y;
  int l0 = ch * 128;
  __shared__ float wl[128];
  __shared__ float Al[512];
  int tid = threadIdx.x, lane = tid & 63, wv = tid >> 6;

  // combine: A[k] = exp(pm[ch,k] - M[k]) / S[k]
  for (int kk = tid; kk < K_; kk += 256) {
    float pmv[LSPLIT], psv[LSPLIT];
    float M = -INFINITY;
#pragma unroll
    for (int c = 0; c < LSPLIT; ++c) {
      pmv[c] = ws[O_PM + ((size_t)b * LSPLIT + c) * K_ + kk];
      psv[c] = ws[O_PS + ((size_t)b * LSPLIT + c) * K_ + kk];
      M = fmaxf(M, pmv[c]);
    }
    float S = 0.f;
#pragma unroll
    for (int c = 0; c < LSPLIT; ++c) S += psv[c] * expf(pmv[c] - M);
    Al[kk] = expf(pmv[ch] - M) / S;
  }
  __syncthreads();

  const _Float16* lg = reinterpret_cast<const _Float16*>(ws + O_L16) +
                       (size_t)(b * L_ + l0) * K_;
  float a8[8];
#pragma unroll
  for (int i = 0; i < 8; ++i) a8[i] = Al[lane * 8 + i];

  for (int il = 0; il < 32; ++il) {
    int ll = wv * 32 + il;
    f16x8 v = *reinterpret_cast<const f16x8*>(lg + (size_t)ll * K_ + lane * 8);
    float s = 0.f;
#pragma unroll
    for (int i = 0; i < 8; ++i) s += expf((float)v[i]) * a8[i];
#pragma unroll
    for (int off = 32; off > 0; off >>= 1) s += __shfl_xor(s, off);
    if (lane == 0) wl[ll] = s;
  }
  __syncthreads();

  const float* xb = x + (size_t)(b * L_ + l0) * D_;
  int half = tid >> 7;            // 0/1 -> l 0..63 / 64..127
  int dd = (tid & 127) * 4;
  float4 a4 = {0.f, 0.f, 0.f, 0.f};
  for (int l = half * 64; l < half * 64 + 64; ++l) {
    float wgt = wl[l];
    float4 xv = *reinterpret_cast<const float4*>(xb + (size_t)l * D_ + dd);
    a4.x += wgt * xv.x;
    a4.y += wgt * xv.y;
    a4.z += wgt * xv.z;
    a4.w += wgt * xv.w;
  }
  atomicAdd(&ws[O_WX + b * D_ + dd + 0], a4.x);
  atomicAdd(&ws[O_WX + b * D_ + dd + 1], a4.y);
  atomicAdd(&ws[O_WX + b * D_ + dd + 2], a4.z);
  atomicAdd(&ws[O_WX + b * D_ + dd + 3], a4.w);
}

// out[b,d] = (rawscale/L) * (inv*wx/K - meanC[d])
__global__ void k_final(const float* ws, float* out) {
  int i = blockIdx.x * 256 + threadIdx.x;
  int d = i & (D_ - 1);
  out[i] = (ws[O_SCALE + i] * (1.f / L_)) *
           (ws[O_INV + i] * ws[O_WX + i] * (1.f / K_) - ws[O_MEANC + d]);
}

extern "C" void kernel_launch(void* const* d_in, const int* in_sizes, int n_in,
                              void* d_out, int out_size, void* d_ws, size_t ws_size,
                              hipStream_t stream) {
  const float* x = (const float*)d_in[0];
  const float* cent = (const float*)d_in[1];
  float* out = (float*)d_out;
  float* ws = (float*)d_ws;

  k_prep<<<386, 256, 0, stream>>>(cent, ws);
  k_sqacc<<<dim3(B_, D_ / 256, 8), 256, 0, stream>>>(x, ws);
  k_finscale<<<B_ * D_ / 256, 256, 0, stream>>>(ws);
  k_gemm16<<<dim3(L_ / 128, K_ / 256, B_), 256, 0, stream>>>(x, ws);
  k_wsumwx<<<dim3(B_, LSPLIT), 256, 0, stream>>>(x, ws);
  k_final<<<B_ * D_ / 256, 256, 0, stream>>>(ws, out);
}